// Round 6
// baseline (3511.528 us; speedup 1.0000x reference)
//
#include <hip/hip_runtime.h>

// GraphNet forward on MI355X — Round 6: f32 OUTPUT (the round-2..5 defect).
// d_out is FLOAT32 (reference output dtype, per harness contract; misaligned
// bf16-write forensics matched observed absmax 1.039 exactly).
// Pipeline = round-5 literal build, output stores f32:
//  E : ein [4096][160] f32 = concat(edges, nodes[s], nodes[r], g, 0pad)
//  G1: h = relu(ein @ eW1 + eb1)        [4096][4096] bf16 (ws)
//  G2: new_edges = relu(h @ eW2 + eb2)  -> d_out f32 @ +524288 elements
//  S : dense sent/recv agg via chunked f32 segment-sum (8 x [8192][512])
//      + 8 accumulate-GEMM launches into zpre
//  N : new_nodes = relu(relu(nodes@nW1[0:64] + g@nW1[8256:] + nb1 + zpre) @ nW2 + nb2)
// ws: ein 2.62MB | h 33.55MB (reused as agg_s/agg_r after G2) | zpre 2.10MB = 38.27MB.
typedef unsigned short u16;
typedef unsigned int u32;
typedef float f32x4 __attribute__((ext_vector_type(4)));

static __device__ __forceinline__ float bf2f(u16 u) {
  return __uint_as_float(((u32)u) << 16);
}
static __device__ __forceinline__ u16 f2bf(float f) {
  u32 x = __float_as_uint(f);
  return (u16)((x + 0x7fffu + ((x >> 16) & 1u)) >> 16);  // RNE
}

// ---------- e_in builder ----------
__global__ __launch_bounds__(192) void k_build_ein2(const float* __restrict__ edges,
                                                    const float* __restrict__ nodes,
                                                    const float* __restrict__ g,
                                                    const int* __restrict__ senders,
                                                    const int* __restrict__ receivers,
                                                    float* __restrict__ ein) {
  const int e = blockIdx.x;
  const int x = threadIdx.x;
  if (x >= 160) return;
  const int s = senders[e], r = receivers[e];
  float v;
  if (x < 16) v = edges[(long)e * 16 + x];
  else if (x < 80) v = nodes[(long)s * 64 + (x - 16)];
  else if (x < 144) v = nodes[(long)r * 64 + (x - 80)];
  else if (x < 152) v = g[x - 144];
  else v = 0.f;
  ein[(long)e * 160 + x] = v;
}

// ---------- VALU GEMM: C = relu(A @ B + bias) ----------
// A: [M][Kpad] (ABF ? bf16 : f32); B: [Kreal][N] f32 row-major.
// OUTF32: 1 -> C f32, 0 -> C bf16(u16).
template <int ABF, int OUTF32>
__global__ __launch_bounds__(256) void k_vgemm(const void* __restrict__ A,
                                               const float* __restrict__ B,
                                               const float* __restrict__ bias,
                                               void* __restrict__ C,
                                               int M, int N, int Kpad, int Kreal) {
  __shared__ float As[64 * 17];
  __shared__ float Bs[16 * 64];
  const int tid = threadIdx.x;
  const int tx = tid & 15, ty = tid >> 4;
  const int m0 = blockIdx.x * 64, n0 = blockIdx.y * 64;
  float acc[4][4] = {};

  for (int kt = 0; kt < Kpad; kt += 16) {
#pragma unroll
    for (int rep = 0; rep < 4; rep++) {
      int idx = rep * 256 + tid;
      int r = idx >> 4, kk = idx & 15;
      float v;
      if (ABF) v = bf2f(((const u16*)A)[(long)(m0 + r) * Kpad + kt + kk]);
      else v = ((const float*)A)[(long)(m0 + r) * Kpad + kt + kk];
      As[r * 17 + kk] = v;
    }
#pragma unroll
    for (int rep = 0; rep < 4; rep++) {
      int idx = rep * 256 + tid;
      int kk = idx >> 6, n = idx & 63;
      Bs[kk * 64 + n] = (kt + kk < Kreal) ? B[(long)(kt + kk) * N + n0 + n] : 0.f;
    }
    __syncthreads();
#pragma unroll
    for (int kk = 0; kk < 16; kk++) {
      float av[4];
#pragma unroll
      for (int i = 0; i < 4; i++) av[i] = As[(ty * 4 + i) * 17 + kk];
      f32x4 b = *(const f32x4*)&Bs[kk * 64 + tx * 4];
#pragma unroll
      for (int i = 0; i < 4; i++)
#pragma unroll
        for (int j = 0; j < 4; j++) acc[i][j] += av[i] * b[j];
    }
    __syncthreads();
  }
#pragma unroll
  for (int i = 0; i < 4; i++) {
#pragma unroll
    for (int j = 0; j < 4; j++) {
      int row = m0 + ty * 4 + i, col = n0 + tx * 4 + j;
      float v = fmaxf(acc[i][j] + bias[col], 0.f);
      if (OUTF32) ((float*)C)[(long)row * N + col] = v;
      else ((u16*)C)[(long)row * N + col] = f2bf(v);
    }
  }
}

// ---------- literal segment-sum, one 512-col chunk (new_edges is f32 now) ----------
__global__ __launch_bounds__(256) void k_segsum(const float* __restrict__ ne,
                                                const int* __restrict__ senders,
                                                const int* __restrict__ receivers,
                                                float* __restrict__ agg_s,
                                                float* __restrict__ agg_r, int c0) {
  const int e = blockIdx.x;
  const int t = threadIdx.x;
  const int s = senders[e], r = receivers[e];
  for (int c = t; c < 512; c += 256) {
    float v = ne[(long)e * 4096 + c0 + c];
    atomicAdd(&agg_s[(long)s * 512 + c], v);
    atomicAdd(&agg_r[(long)r * 512 + c], v);
  }
}

// ---------- zpre += agg_s @ nW1[64+c0..] + agg_r @ nW1[4160+c0..] ----------
__global__ __launch_bounds__(256) void k_accgemm(const float* __restrict__ agg_s,
                                                 const float* __restrict__ agg_r,
                                                 const float* __restrict__ nW1,
                                                 float* __restrict__ zpre, int c0) {
  long idx = (long)blockIdx.x * 256 + threadIdx.x;  // [0, 524288)
  int n = idx >> 6, col = idx & 63;
  float sum = 0.f;
  const float* Ws = nW1 + (long)(64 + c0) * 64 + col;
  const float* Wr = nW1 + (long)(4160 + c0) * 64 + col;
  const float* as = agg_s + (long)n * 512;
  const float* ar = agg_r + (long)n * 512;
  for (int k = 0; k < 512; k++) {
    sum += as[k] * Ws[(long)k * 64];
    sum += ar[k] * Wr[(long)k * 64];
  }
  zpre[idx] += sum;
}

// ---------- final node MLP, pure f32, f32 output ----------
__global__ __launch_bounds__(256) void k_final(const float* __restrict__ nodes,
                                               const float* __restrict__ g,
                                               const float* __restrict__ nW1,
                                               const float* __restrict__ nb1,
                                               const float* __restrict__ nW2,
                                               const float* __restrict__ nb2,
                                               const float* __restrict__ zpre,
                                               float* __restrict__ out0) {
  __shared__ float h2[64 * 64];
  __shared__ float gb[64];
  const int tid = threadIdx.x;
  const long n0 = (long)blockIdx.x * 64;
  if (tid < 64) {
    float s = nb1[tid];
#pragma unroll
    for (int j = 0; j < 8; j++) s += g[j] * nW1[(long)(8256 + j) * 64 + tid];
    gb[tid] = s;
  }
  __syncthreads();
#pragma unroll 2
  for (int rep = 0; rep < 16; rep++) {
    int idx = rep * 256 + tid;  // 0..4095
    int i = idx >> 6, c = idx & 63;
    float z = gb[c] + zpre[(n0 + i) * 64 + c];
    const float* nr = nodes + (n0 + i) * 64;
#pragma unroll 8
    for (int k = 0; k < 64; k++) z += nr[k] * nW1[(long)k * 64 + c];
    h2[idx] = fmaxf(z, 0.f);
  }
  __syncthreads();
#pragma unroll 2
  for (int rep = 0; rep < 16; rep++) {
    int idx = rep * 256 + tid;
    int i = idx >> 6, c = idx & 63;
    float z = nb2[c];
#pragma unroll 8
    for (int k = 0; k < 64; k++) z += h2[i * 64 + k] * nW2[(long)k * 64 + c];
    out0[(n0 + i) * 64 + c] = fmaxf(z, 0.f);
  }
}

extern "C" void kernel_launch(void* const* d_in, const int* in_sizes, int n_in,
                              void* d_out, int out_size, void* d_ws, size_t ws_size,
                              hipStream_t stream) {
  const float* nodes = (const float*)d_in[0];
  const float* edges = (const float*)d_in[1];
  const float* g = (const float*)d_in[2];
  const int* senders = (const int*)d_in[3];
  const int* receivers = (const int*)d_in[4];
  const float* eW1 = (const float*)d_in[5];
  const float* eb1 = (const float*)d_in[6];
  const float* eW2 = (const float*)d_in[7];
  const float* eb2 = (const float*)d_in[8];
  const float* nW1 = (const float*)d_in[9];
  const float* nb1 = (const float*)d_in[10];
  const float* nW2 = (const float*)d_in[11];
  const float* nb2 = (const float*)d_in[12];

  char* ws = (char*)d_ws;
  float* ein = (float*)ws;                 // [4096][160] f32    2,621,440 B
  u16* h = (u16*)(ws + 2621440);           // [4096][4096] bf16 33,554,432 B
  float* agg_s = (float*)(ws + 2621440);   // [8192][512] f32 (overlays h after G2)
  float* agg_r = (float*)(ws + 19398656);  // [8192][512] f32
  float* zpre = (float*)(ws + 36175872);   // [8192][64] f32     2,097,152 B

  float* out_nodes = (float*)d_out;            // [8192][64] f32
  float* out_edges = (float*)d_out + 524288;   // [4096][4096] f32

  dim3 b256(256);
  k_build_ein2<<<4096, 192, 0, stream>>>(edges, nodes, g, senders, receivers, ein);
  k_vgemm<0, 0><<<dim3(64, 64), b256, 0, stream>>>(ein, eW1, eb1, h, 4096, 4096, 160, 152);
  k_vgemm<1, 1><<<dim3(64, 64), b256, 0, stream>>>(h, eW2, eb2, out_edges, 4096, 4096, 4096,
                                                   4096);

  // h is dead now; its region becomes agg_s/agg_r.
  hipMemsetAsync(zpre, 0, 2097152, stream);
  for (int c0 = 0; c0 < 4096; c0 += 512) {
    hipMemsetAsync((void*)agg_s, 0, 33554432, stream);  // agg_s + agg_r contiguous
    k_segsum<<<4096, b256, 0, stream>>>(out_edges, senders, receivers, agg_s, agg_r, c0);
    k_accgemm<<<2048, b256, 0, stream>>>(agg_s, agg_r, nW1, zpre, c0);
  }
  k_final<<<128, b256, 0, stream>>>(nodes, g, nW1, nb1, nW2, nb2, zpre, out_nodes);
}

// Round 7
// 416.755 us; speedup vs baseline: 8.4259x; 8.4259x over previous
//
#include <hip/hip_runtime.h>

// GraphNet forward on MI355X — Round 7: MFMA front half + lean validated tail.
//  T1: eW1 [152,4096] -> eW1T [4096,160] bf16 (zero-pad K to 160)
//  T2: eW2 [4096,4096] -> eW2T [4096,4096] bf16
//  E : ein [4096,160] bf16 = concat(edges, nodes[s], nodes[r], g, 0pad)
//  G1: h = relu(ein @ eW1 + eb1)        [4096,4096] bf16   (MFMA, gload_lds)
//  G2: new_edges = relu(h @ eW2 + eb2)  -> d_out f32 @+524288 (MFMA)
//  S : accb += scatter_{s|r}(new_edges @ nW1[64..8255])  (VALU GEMM + atomics)
//  N : new_nodes = relu(relu(nodes@nW1[0:64] + g@nW1[8256:] + nb1 + accb) @ nW2 + nb2)
// Validation state: front half byte-validated (round2 MFMA == round3 VALU);
// tail algebra validated round 6; scatter inner loop is a copy of validated
// k_vgemm with atomic epilogue. Output f32 (round-6 resolution).
// ws (70.5MB, inside validated envelope):
//   [0,2MB)        eW1T (1.31MB, dies after G1) then accb (2MB, memset before S)
//   [2MB, 3.3MB)   ein bf16
//   [3.3MB,37MB)   eW2T bf16
//   [37MB,70.5MB)  h bf16
typedef unsigned short u16;
typedef unsigned int u32;
typedef __bf16 bf16x8 __attribute__((ext_vector_type(8)));
typedef float f32x4 __attribute__((ext_vector_type(4)));

static __device__ __forceinline__ float bf2f(u16 u) {
  return __uint_as_float(((u32)u) << 16);
}
static __device__ __forceinline__ u16 f2bf(float f) {
  u32 x = __float_as_uint(f);
  return (u16)((x + 0x7fffu + ((x >> 16) & 1u)) >> 16);  // RNE
}
// async global->LDS, 16B per lane (m97 pattern: LDS dest wave-uniform+lane*16)
static __device__ __forceinline__ void gl_lds16(const u16* g, u16* l) {
  __builtin_amdgcn_global_load_lds(
      (const __attribute__((address_space(1))) void*)g,
      (__attribute__((address_space(3))) void*)l, 16, 0, 0);
}

// ---------- transpose f32[K][N] -> bf16[N][Kpad], zero-pad K..Kpad ----------
__global__ __launch_bounds__(256) void k_transpose(const float* __restrict__ in,
                                                   u16* __restrict__ out,
                                                   int K, int N, int Kpad) {
  __shared__ u16 t[64 * 65];
  const int k0 = blockIdx.x * 64;
  const int n0 = blockIdx.y * 64;
  const int tid = threadIdx.x;
#pragma unroll
  for (int rep = 0; rep < 16; rep++) {
    int idx = rep * 256 + tid;
    int ki = idx >> 6, nj = idx & 63;
    float v = (k0 + ki < K) ? in[(long)(k0 + ki) * N + n0 + nj] : 0.f;
    t[ki * 65 + nj] = f2bf(v);
  }
  __syncthreads();
#pragma unroll
  for (int rep = 0; rep < 16; rep++) {
    int idx = rep * 256 + tid;
    int ni = idx >> 6, kj = idx & 63;
    if (k0 + kj < Kpad) out[(long)(n0 + ni) * Kpad + (k0 + kj)] = t[kj * 65 + ni];
  }
}

// ---------- e_in builder: [4096][160] bf16 ----------
__global__ __launch_bounds__(192) void k_build_ein(const float* __restrict__ edges,
                                                   const float* __restrict__ nodes,
                                                   const float* __restrict__ g,
                                                   const int* __restrict__ senders,
                                                   const int* __restrict__ receivers,
                                                   u16* __restrict__ ein) {
  const int e = blockIdx.x;
  const int x = threadIdx.x;
  if (x >= 160) return;
  const int s = senders[e], r = receivers[e];
  float v;
  if (x < 16) v = edges[(long)e * 16 + x];
  else if (x < 80) v = nodes[(long)s * 64 + (x - 16)];
  else if (x < 144) v = nodes[(long)r * 64 + (x - 80)];
  else if (x < 152) v = g[x - 144];
  else v = 0.f;
  ein[(long)e * 160 + x] = f2bf(v);
}

// ---------- MFMA GEMM: C = relu(A @ B + bias) ----------
// A:[M][K] bf16, BT:[N][K] bf16, 128x128 tile, BK=32, 4 waves 2x2, 4x4 frags.
// MODE 0: C bf16. MODE 1: C f32. Staging via global_load_lds (async DMA).
template <int MODE>
__global__ __launch_bounds__(256) void k_mgemm(const u16* __restrict__ A,
                                               const u16* __restrict__ BT,
                                               const float* __restrict__ bias,
                                               void* __restrict__ C, int M, int N, int K) {
  __shared__ alignas(16) u16 As[128 * 32];
  __shared__ alignas(16) u16 Bs[128 * 32];
  const int tid = threadIdx.x;
  const int lane = tid & 63, wid = tid >> 6;
  const int wr = wid >> 1, wc = wid & 1;
  const int m0 = blockIdx.x * 128, n0 = blockIdx.y * 128;
  const int lr = lane & 15, lk = lane >> 4;

  f32x4 acc[4][4];
#pragma unroll
  for (int i = 0; i < 4; i++)
#pragma unroll
    for (int j = 0; j < 4; j++) acc[i][j] = {0.f, 0.f, 0.f, 0.f};

  for (int kt = 0; kt < K; kt += 32) {
#pragma unroll
    for (int rep = 0; rep < 2; rep++) {
      int o = rep * 2048 + tid * 8;        // LDS elem offset; bytes = wavebase + lane*16
      int row = o >> 5, kk = o & 31;
      gl_lds16(&A[(long)(m0 + row) * K + kt + kk], &As[o]);
      gl_lds16(&BT[(long)(n0 + row) * K + kt + kk], &Bs[o]);
    }
    __syncthreads();
    bf16x8 af[4], bfr[4];
#pragma unroll
    for (int mi = 0; mi < 4; mi++)
      af[mi] = *(const bf16x8*)&As[(wr * 64 + mi * 16 + lr) * 32 + lk * 8];
#pragma unroll
    for (int ni = 0; ni < 4; ni++)
      bfr[ni] = *(const bf16x8*)&Bs[(wc * 64 + ni * 16 + lr) * 32 + lk * 8];
#pragma unroll
    for (int mi = 0; mi < 4; mi++)
#pragma unroll
      for (int ni = 0; ni < 4; ni++)
        acc[mi][ni] =
            __builtin_amdgcn_mfma_f32_16x16x32_bf16(af[mi], bfr[ni], acc[mi][ni], 0, 0, 0);
    __syncthreads();
  }
#pragma unroll
  for (int ni = 0; ni < 4; ni++) {
    int col = n0 + wc * 64 + ni * 16 + lr;
    float bb = bias[col];
#pragma unroll
    for (int mi = 0; mi < 4; mi++) {
      int row = m0 + wr * 64 + mi * 16 + lk * 4;
#pragma unroll
      for (int r = 0; r < 4; r++) {
        float v = fmaxf(acc[mi][ni][r] + bb, 0.f);
        if (MODE == 0) ((u16*)C)[(long)(row + r) * N + col] = f2bf(v);
        else ((float*)C)[(long)(row + r) * N + col] = v;
      }
    }
  }
}

// ---------- scatter VALU GEMM: accb += scatter(new_edges @ nW1-mid) ----------
// E f32 [4096][4096]; B = nW1 + (64 + half*4096)*64 (f32 [4096][64]).
// half 0 -> senders (W_s), half 1 -> receivers (W_r). grid (64, 2, 4 ksplit).
// Inner loop structurally identical to round-6-validated k_vgemm.
__global__ __launch_bounds__(256) void k_scatter_v(const float* __restrict__ E,
                                                   const float* __restrict__ nW1,
                                                   const int* __restrict__ senders,
                                                   const int* __restrict__ receivers,
                                                   float* __restrict__ accb) {
  __shared__ float As[64 * 17];
  __shared__ float Bs[16 * 64];
  const int tid = threadIdx.x;
  const int tx = tid & 15, ty = tid >> 4;
  const int m0 = blockIdx.x * 64;
  const int half = blockIdx.y;
  const int kbase = blockIdx.z * 1024;
  const float* B = nW1 + (long)(64 + half * 4096) * 64;
  const int* idxarr = half ? receivers : senders;
  float acc[4][4] = {};

  for (int kt = kbase; kt < kbase + 1024; kt += 16) {
#pragma unroll
    for (int rep = 0; rep < 4; rep++) {
      int idx = rep * 256 + tid;
      int r = idx >> 4, kk = idx & 15;
      As[r * 17 + kk] = E[(long)(m0 + r) * 4096 + kt + kk];
    }
#pragma unroll
    for (int rep = 0; rep < 4; rep++) {
      int idx = rep * 256 + tid;
      int kk = idx >> 6, n = idx & 63;
      Bs[kk * 64 + n] = B[(long)(kt + kk) * 64 + n];
    }
    __syncthreads();
#pragma unroll
    for (int kk = 0; kk < 16; kk++) {
      float av[4];
#pragma unroll
      for (int i = 0; i < 4; i++) av[i] = As[(ty * 4 + i) * 17 + kk];
      f32x4 b = *(const f32x4*)&Bs[kk * 64 + tx * 4];
#pragma unroll
      for (int i = 0; i < 4; i++)
#pragma unroll
        for (int j = 0; j < 4; j++) acc[i][j] += av[i] * b[j];
    }
    __syncthreads();
  }
#pragma unroll
  for (int i = 0; i < 4; i++) {
    int e = m0 + ty * 4 + i;
    int tgt = idxarr[e];
#pragma unroll
    for (int j = 0; j < 4; j++)
      atomicAdd(&accb[(long)tgt * 64 + tx * 4 + j], acc[i][j]);
  }
}

// ---------- final node MLP, pure f32 (round-6 validated) ----------
__global__ __launch_bounds__(256) void k_final(const float* __restrict__ nodes,
                                               const float* __restrict__ g,
                                               const float* __restrict__ nW1,
                                               const float* __restrict__ nb1,
                                               const float* __restrict__ nW2,
                                               const float* __restrict__ nb2,
                                               const float* __restrict__ zpre,
                                               float* __restrict__ out0) {
  __shared__ float h2[64 * 64];
  __shared__ float gb[64];
  const int tid = threadIdx.x;
  const long n0 = (long)blockIdx.x * 64;
  if (tid < 64) {
    float s = nb1[tid];
#pragma unroll
    for (int j = 0; j < 8; j++) s += g[j] * nW1[(long)(8256 + j) * 64 + tid];
    gb[tid] = s;
  }
  __syncthreads();
#pragma unroll 2
  for (int rep = 0; rep < 16; rep++) {
    int idx = rep * 256 + tid;
    int i = idx >> 6, c = idx & 63;
    float z = gb[c] + zpre[(n0 + i) * 64 + c];
    const float* nr = nodes + (n0 + i) * 64;
#pragma unroll 8
    for (int k = 0; k < 64; k++) z += nr[k] * nW1[(long)k * 64 + c];
    h2[idx] = fmaxf(z, 0.f);
  }
  __syncthreads();
#pragma unroll 2
  for (int rep = 0; rep < 16; rep++) {
    int idx = rep * 256 + tid;
    int i = idx >> 6, c = idx & 63;
    float z = nb2[c];
#pragma unroll 8
    for (int k = 0; k < 64; k++) z += h2[i * 64 + k] * nW2[(long)k * 64 + c];
    out0[(n0 + i) * 64 + c] = fmaxf(z, 0.f);
  }
}

extern "C" void kernel_launch(void* const* d_in, const int* in_sizes, int n_in,
                              void* d_out, int out_size, void* d_ws, size_t ws_size,
                              hipStream_t stream) {
  const float* nodes = (const float*)d_in[0];
  const float* edges = (const float*)d_in[1];
  const float* g = (const float*)d_in[2];
  const int* senders = (const int*)d_in[3];
  const int* receivers = (const int*)d_in[4];
  const float* eW1 = (const float*)d_in[5];
  const float* eb1 = (const float*)d_in[6];
  const float* eW2 = (const float*)d_in[7];
  const float* eb2 = (const float*)d_in[8];
  const float* nW1 = (const float*)d_in[9];
  const float* nb1 = (const float*)d_in[10];
  const float* nW2 = (const float*)d_in[11];
  const float* nb2 = (const float*)d_in[12];

  char* ws = (char*)d_ws;
  u16* eW1T = (u16*)(ws + 0);              // [4096][160] bf16, dies after G1
  float* accb = (float*)(ws + 0);          // [8192][64] f32, live after memset
  u16* ein = (u16*)(ws + 2097152);         // [4096][160] bf16
  u16* eW2T = (u16*)(ws + 3407872);        // [4096][4096] bf16
  u16* h = (u16*)(ws + 36962304);          // [4096][4096] bf16  (ends 70.5MB)

  float* out_nodes = (float*)d_out;            // [8192][64] f32
  float* out_edges = (float*)d_out + 524288;   // [4096][4096] f32

  dim3 b256(256);
  k_transpose<<<dim3(3, 64), b256, 0, stream>>>(eW1, eW1T, 152, 4096, 160);
  k_transpose<<<dim3(64, 64), b256, 0, stream>>>(eW2, eW2T, 4096, 4096, 4096);
  k_build_ein<<<4096, 192, 0, stream>>>(edges, nodes, g, senders, receivers, ein);

  k_mgemm<0><<<dim3(32, 32), b256, 0, stream>>>(ein, eW1T, eb1, h, 4096, 4096, 160);
  k_mgemm<1><<<dim3(32, 32), b256, 0, stream>>>(h, eW2T, eb2, out_edges, 4096, 4096, 4096);

  hipMemsetAsync(accb, 0, 8192 * 64 * 4, stream);  // clobbers dead eW1T
  k_scatter_v<<<dim3(64, 2, 4), b256, 0, stream>>>(out_edges, nW1, senders, receivers, accb);
  k_final<<<128, b256, 0, stream>>>(nodes, g, nW1, nb1, nW2, nb2, accb, out_nodes);
}

// Round 8
// 320.261 us; speedup vs baseline: 10.9646x; 1.3013x over previous
//
#include <hip/hip_runtime.h>

// GraphNet forward on MI355X — Round 8: deep-pipelined 256^2 G2.
//  T1: eW1 [152,4096] -> eW1T [4096,160] bf16 (zero-pad K to 160)
//  T2: eW2 [4096,4096] -> eW2T [4096,4096] bf16
//  E : ein [4096,160] bf16 = concat(edges, nodes[s], nodes[r], g, 0pad)
//  G1: h = relu(ein @ eW1 + eb1)        [4096,4096] bf16   (128^2 m97-style)
//  G2: new_edges = relu(h @ eW2 + eb2)  -> d_out f32       (NEW: 256^2 tile,
//       8 waves, BK=32, 4-buffer LDS pipeline, counted vmcnt(8), 1 barrier/K-tile,
//       XOR-swizzled LDS via pre-swizzled global source per rule 21)
//  S : accb += scatter_{s|r}(new_edges @ nW1[64..8255])  (VALU GEMM + atomics)
//  N : new_nodes = relu(relu(nodes@nW1[0:64] + g@nW1[8256:] + nb1 + accb) @ nW2 + nb2)
// Output f32 (round-6). ws 70.5MB (validated by round-7 pass).
typedef unsigned short u16;
typedef unsigned int u32;
typedef __bf16 bf16x8 __attribute__((ext_vector_type(8)));
typedef float f32x4 __attribute__((ext_vector_type(4)));

static __device__ __forceinline__ float bf2f(u16 u) {
  return __uint_as_float(((u32)u) << 16);
}
static __device__ __forceinline__ u16 f2bf(float f) {
  u32 x = __float_as_uint(f);
  return (u16)((x + 0x7fffu + ((x >> 16) & 1u)) >> 16);  // RNE
}
static __device__ __forceinline__ void gl_lds16(const u16* g, u16* l) {
  __builtin_amdgcn_global_load_lds(
      (const __attribute__((address_space(1))) void*)g,
      (__attribute__((address_space(3))) void*)l, 16, 0, 0);
}

// ---------- transpose f32[K][N] -> bf16[N][Kpad], zero-pad K..Kpad ----------
__global__ __launch_bounds__(256) void k_transpose(const float* __restrict__ in,
                                                   u16* __restrict__ out,
                                                   int K, int N, int Kpad) {
  __shared__ u16 t[64 * 65];
  const int k0 = blockIdx.x * 64;
  const int n0 = blockIdx.y * 64;
  const int tid = threadIdx.x;
#pragma unroll
  for (int rep = 0; rep < 16; rep++) {
    int idx = rep * 256 + tid;
    int ki = idx >> 6, nj = idx & 63;
    float v = (k0 + ki < K) ? in[(long)(k0 + ki) * N + n0 + nj] : 0.f;
    t[ki * 65 + nj] = f2bf(v);
  }
  __syncthreads();
#pragma unroll
  for (int rep = 0; rep < 16; rep++) {
    int idx = rep * 256 + tid;
    int ni = idx >> 6, kj = idx & 63;
    if (k0 + kj < Kpad) out[(long)(n0 + ni) * Kpad + (k0 + kj)] = t[kj * 65 + ni];
  }
}

// ---------- e_in builder: [4096][160] bf16 ----------
__global__ __launch_bounds__(192) void k_build_ein(const float* __restrict__ edges,
                                                   const float* __restrict__ nodes,
                                                   const float* __restrict__ g,
                                                   const int* __restrict__ senders,
                                                   const int* __restrict__ receivers,
                                                   u16* __restrict__ ein) {
  const int e = blockIdx.x;
  const int x = threadIdx.x;
  if (x >= 160) return;
  const int s = senders[e], r = receivers[e];
  float v;
  if (x < 16) v = edges[(long)e * 16 + x];
  else if (x < 80) v = nodes[(long)s * 64 + (x - 16)];
  else if (x < 144) v = nodes[(long)r * 64 + (x - 80)];
  else if (x < 152) v = g[x - 144];
  else v = 0.f;
  ein[(long)e * 160 + x] = f2bf(v);
}

// ---------- 128^2 MFMA GEMM (round-7 validated) — used for G1 ----------
template <int MODE>
__global__ __launch_bounds__(256) void k_mgemm(const u16* __restrict__ A,
                                               const u16* __restrict__ BT,
                                               const float* __restrict__ bias,
                                               void* __restrict__ C, int M, int N, int K) {
  __shared__ alignas(16) u16 As[128 * 32];
  __shared__ alignas(16) u16 Bs[128 * 32];
  const int tid = threadIdx.x;
  const int lane = tid & 63, wid = tid >> 6;
  const int wr = wid >> 1, wc = wid & 1;
  const int m0 = blockIdx.x * 128, n0 = blockIdx.y * 128;
  const int lr = lane & 15, lk = lane >> 4;

  f32x4 acc[4][4];
#pragma unroll
  for (int i = 0; i < 4; i++)
#pragma unroll
    for (int j = 0; j < 4; j++) acc[i][j] = {0.f, 0.f, 0.f, 0.f};

  for (int kt = 0; kt < K; kt += 32) {
#pragma unroll
    for (int rep = 0; rep < 2; rep++) {
      int o = rep * 2048 + tid * 8;
      int row = o >> 5, kk = o & 31;
      gl_lds16(&A[(long)(m0 + row) * K + kt + kk], &As[o]);
      gl_lds16(&BT[(long)(n0 + row) * K + kt + kk], &Bs[o]);
    }
    __syncthreads();
    bf16x8 af[4], bfr[4];
#pragma unroll
    for (int mi = 0; mi < 4; mi++)
      af[mi] = *(const bf16x8*)&As[(wr * 64 + mi * 16 + lr) * 32 + lk * 8];
#pragma unroll
    for (int ni = 0; ni < 4; ni++)
      bfr[ni] = *(const bf16x8*)&Bs[(wc * 64 + ni * 16 + lr) * 32 + lk * 8];
#pragma unroll
    for (int mi = 0; mi < 4; mi++)
#pragma unroll
      for (int ni = 0; ni < 4; ni++)
        acc[mi][ni] =
            __builtin_amdgcn_mfma_f32_16x16x32_bf16(af[mi], bfr[ni], acc[mi][ni], 0, 0, 0);
    __syncthreads();
  }
#pragma unroll
  for (int ni = 0; ni < 4; ni++) {
    int col = n0 + wc * 64 + ni * 16 + lr;
    float bb = bias[col];
#pragma unroll
    for (int mi = 0; mi < 4; mi++) {
      int row = m0 + wr * 64 + mi * 16 + lk * 4;
#pragma unroll
      for (int r = 0; r < 4; r++) {
        float v = fmaxf(acc[mi][ni][r] + bb, 0.f);
        if (MODE == 0) ((u16*)C)[(long)(row + r) * N + col] = f2bf(v);
        else ((float*)C)[(long)(row + r) * N + col] = v;
      }
    }
  }
}

// ---------- 256^2 deep-pipelined MFMA GEMM — G2 ----------
// 512 thr = 8 waves (2M x 4N); per wave 128x64 out = acc[8][4] 16x16 frags.
// BK=32; LDS = 4 K-tile buffers x (A 16KB + B 16KB) = 128KB.
// Pipeline: stage lead 3 K-tiles; per iter: vmcnt(8) -> s_barrier ->
// stage(t+3) -> ds_read frags(t) -> 32 MFMA. vmcnt counts per wave: 4 gl_lds
// per K-tile per wave; at iter top 12 outstanding (t,t+1,t+2); vmcnt(8) lands
// tile t; barrier publishes all waves' stages. Stage(t+3) overwrites buf
// (t-1)&3 whose readers passed this barrier. Swizzle: granule ^= (row&3),
// applied to global SOURCE at stage and to LDS read addr (involution).
__global__ __launch_bounds__(512, 1) void k_gemm256(const u16* __restrict__ A,
                                                    const u16* __restrict__ BT,
                                                    const float* __restrict__ bias,
                                                    float* __restrict__ C, int N, int K) {
  __shared__ alignas(16) u16 lds[65536];  // 128 KB
  const int tid = threadIdx.x;
  const int lane = tid & 63, wid = tid >> 6;
  const int wr = wid >> 2, wc = wid & 3;
  const int m0 = blockIdx.x * 256, n0 = blockIdx.y * 256;
  const int lr = lane & 15, lk = lane >> 4;
  const int swz = (lk ^ (lr & 3)) << 3;  // u16 offset of swizzled 16B granule
  const int NT = K >> 5;

  // stage source mapping (per lane): row-in-half, swizzled granule
  const int srow = wid * 16 + (lane >> 2);
  const int sq = ((lane & 3) ^ ((lane >> 2) & 3)) << 3;  // u16 offset in row
  const int sdst = wid * 512 + lane * 8;                 // linear LDS (u16)

  f32x4 acc[8][4];
#pragma unroll
  for (int i = 0; i < 8; i++)
#pragma unroll
    for (int j = 0; j < 4; j++) acc[i][j] = {0.f, 0.f, 0.f, 0.f};

#define STAGE_TILE(T)                                                              \
  {                                                                                \
    const int kt_ = (T) * 32;                                                      \
    u16* Ab_ = &lds[((T) & 3) * 16384];                                            \
    u16* Bb_ = Ab_ + 8192;                                                         \
    gl_lds16(&A[(long)(m0 + srow) * K + kt_ + sq], Ab_ + sdst);                    \
    gl_lds16(&A[(long)(m0 + 128 + srow) * K + kt_ + sq], Ab_ + 4096 + sdst);       \
    gl_lds16(&BT[(long)(n0 + srow) * K + kt_ + sq], Bb_ + sdst);                   \
    gl_lds16(&BT[(long)(n0 + 128 + srow) * K + kt_ + sq], Bb_ + 4096 + sdst);      \
  }

  STAGE_TILE(0)
  STAGE_TILE(1)
  STAGE_TILE(2)

  for (int t = 0; t < NT; t++) {
    if (t < NT - 2) {
      asm volatile("s_waitcnt vmcnt(8)" ::: "memory");
    } else if (t == NT - 2) {
      asm volatile("s_waitcnt vmcnt(4)" ::: "memory");
    } else {
      asm volatile("s_waitcnt vmcnt(0)" ::: "memory");
    }
    __builtin_amdgcn_s_barrier();
    if (t + 3 < NT) STAGE_TILE(t + 3)

    const u16* Ab = &lds[(t & 3) * 16384];
    const u16* Bb = Ab + 8192;
    bf16x8 af[8], bfr[4];
#pragma unroll
    for (int mi = 0; mi < 8; mi++)
      af[mi] = *(const bf16x8*)&Ab[(wr * 128 + mi * 16 + lr) * 32 + swz];
#pragma unroll
    for (int ni = 0; ni < 4; ni++)
      bfr[ni] = *(const bf16x8*)&Bb[(wc * 64 + ni * 16 + lr) * 32 + swz];
#pragma unroll
    for (int mi = 0; mi < 8; mi++)
#pragma unroll
      for (int ni = 0; ni < 4; ni++)
        acc[mi][ni] =
            __builtin_amdgcn_mfma_f32_16x16x32_bf16(af[mi], bfr[ni], acc[mi][ni], 0, 0, 0);
  }
#undef STAGE_TILE

#pragma unroll
  for (int ni = 0; ni < 4; ni++) {
    int col = n0 + wc * 64 + ni * 16 + lr;
    float bb = bias[col];
#pragma unroll
    for (int mi = 0; mi < 8; mi++) {
      int row = m0 + wr * 128 + mi * 16 + lk * 4;
#pragma unroll
      for (int r = 0; r < 4; r++)
        C[(long)(row + r) * N + col] = fmaxf(acc[mi][ni][r] + bb, 0.f);
    }
  }
}

// ---------- scatter VALU GEMM (round-7 validated) ----------
__global__ __launch_bounds__(256) void k_scatter_v(const float* __restrict__ E,
                                                   const float* __restrict__ nW1,
                                                   const int* __restrict__ senders,
                                                   const int* __restrict__ receivers,
                                                   float* __restrict__ accb) {
  __shared__ float As[64 * 17];
  __shared__ float Bs[16 * 64];
  const int tid = threadIdx.x;
  const int tx = tid & 15, ty = tid >> 4;
  const int m0 = blockIdx.x * 64;
  const int half = blockIdx.y;
  const int kbase = blockIdx.z * 1024;
  const float* B = nW1 + (long)(64 + half * 4096) * 64;
  const int* idxarr = half ? receivers : senders;
  float acc[4][4] = {};

  for (int kt = kbase; kt < kbase + 1024; kt += 16) {
#pragma unroll
    for (int rep = 0; rep < 4; rep++) {
      int idx = rep * 256 + tid;
      int r = idx >> 4, kk = idx & 15;
      As[r * 17 + kk] = E[(long)(m0 + r) * 4096 + kt + kk];
    }
#pragma unroll
    for (int rep = 0; rep < 4; rep++) {
      int idx = rep * 256 + tid;
      int kk = idx >> 6, n = idx & 63;
      Bs[kk * 64 + n] = B[(long)(kt + kk) * 64 + n];
    }
    __syncthreads();
#pragma unroll
    for (int kk = 0; kk < 16; kk++) {
      float av[4];
#pragma unroll
      for (int i = 0; i < 4; i++) av[i] = As[(ty * 4 + i) * 17 + kk];
      f32x4 b = *(const f32x4*)&Bs[kk * 64 + tx * 4];
#pragma unroll
      for (int i = 0; i < 4; i++)
#pragma unroll
        for (int j = 0; j < 4; j++) acc[i][j] += av[i] * b[j];
    }
    __syncthreads();
  }
#pragma unroll
  for (int i = 0; i < 4; i++) {
    int e = m0 + ty * 4 + i;
    int tgt = idxarr[e];
#pragma unroll
    for (int j = 0; j < 4; j++)
      atomicAdd(&accb[(long)tgt * 64 + tx * 4 + j], acc[i][j]);
  }
}

// ---------- final node MLP, pure f32 (round-6 validated) ----------
__global__ __launch_bounds__(256) void k_final(const float* __restrict__ nodes,
                                               const float* __restrict__ g,
                                               const float* __restrict__ nW1,
                                               const float* __restrict__ nb1,
                                               const float* __restrict__ nW2,
                                               const float* __restrict__ nb2,
                                               const float* __restrict__ zpre,
                                               float* __restrict__ out0) {
  __shared__ float h2[64 * 64];
  __shared__ float gb[64];
  const int tid = threadIdx.x;
  const long n0 = (long)blockIdx.x * 64;
  if (tid < 64) {
    float s = nb1[tid];
#pragma unroll
    for (int j = 0; j < 8; j++) s += g[j] * nW1[(long)(8256 + j) * 64 + tid];
    gb[tid] = s;
  }
  __syncthreads();
#pragma unroll 2
  for (int rep = 0; rep < 16; rep++) {
    int idx = rep * 256 + tid;
    int i = idx >> 6, c = idx & 63;
    float z = gb[c] + zpre[(n0 + i) * 64 + c];
    const float* nr = nodes + (n0 + i) * 64;
#pragma unroll 8
    for (int k = 0; k < 64; k++) z += nr[k] * nW1[(long)k * 64 + c];
    h2[idx] = fmaxf(z, 0.f);
  }
  __syncthreads();
#pragma unroll 2
  for (int rep = 0; rep < 16; rep++) {
    int idx = rep * 256 + tid;
    int i = idx >> 6, c = idx & 63;
    float z = nb2[c];
#pragma unroll 8
    for (int k = 0; k < 64; k++) z += h2[i * 64 + k] * nW2[(long)k * 64 + c];
    out0[(n0 + i) * 64 + c] = fmaxf(z, 0.f);
  }
}

extern "C" void kernel_launch(void* const* d_in, const int* in_sizes, int n_in,
                              void* d_out, int out_size, void* d_ws, size_t ws_size,
                              hipStream_t stream) {
  const float* nodes = (const float*)d_in[0];
  const float* edges = (const float*)d_in[1];
  const float* g = (const float*)d_in[2];
  const int* senders = (const int*)d_in[3];
  const int* receivers = (const int*)d_in[4];
  const float* eW1 = (const float*)d_in[5];
  const float* eb1 = (const float*)d_in[6];
  const float* eW2 = (const float*)d_in[7];
  const float* eb2 = (const float*)d_in[8];
  const float* nW1 = (const float*)d_in[9];
  const float* nb1 = (const float*)d_in[10];
  const float* nW2 = (const float*)d_in[11];
  const float* nb2 = (const float*)d_in[12];

  char* ws = (char*)d_ws;
  u16* eW1T = (u16*)(ws + 0);       // [4096][160] bf16, dies after G1
  float* accb = (float*)(ws + 0);   // [8192][64] f32, live after memset
  u16* ein = (u16*)(ws + 2097152);  // [4096][160] bf16
  u16* eW2T = (u16*)(ws + 3407872); // [4096][4096] bf16
  u16* h = (u16*)(ws + 36962304);   // [4096][4096] bf16  (ends 70.5MB)

  float* out_nodes = (float*)d_out;
  float* out_edges = (float*)d_out + 524288;

  dim3 b256(256);
  k_transpose<<<dim3(3, 64), b256, 0, stream>>>(eW1, eW1T, 152, 4096, 160);
  k_transpose<<<dim3(64, 64), b256, 0, stream>>>(eW2, eW2T, 4096, 4096, 4096);
  k_build_ein<<<4096, 192, 0, stream>>>(edges, nodes, g, senders, receivers, ein);

  k_mgemm<0><<<dim3(32, 32), b256, 0, stream>>>(ein, eW1T, eb1, h, 4096, 4096, 160);
  k_gemm256<<<dim3(16, 16), dim3(512), 0, stream>>>(h, eW2T, eb2, out_edges, 4096, 4096);

  hipMemsetAsync(accb, 0, 8192 * 64 * 4, stream);
  k_scatter_v<<<dim3(64, 2, 4), b256, 0, stream>>>(out_edges, nW1, senders, receivers, accb);
  k_final<<<128, b256, 0, stream>>>(nodes, g, nW1, nb1, nW2, nb2, accb, out_nodes);
}

// Round 9
// 263.391 us; speedup vs baseline: 13.3320x; 1.2159x over previous
//
#include <hip/hip_runtime.h>

// GraphNet forward on MI355X — Round 9: corrected LDS swizzle + MFMA scatter.
//  T1: eW1 [152,4096] -> eW1T [4096,160] bf16 (zero-pad K to 160)
//  T2: eW2 [4096,4096] -> eW2T [4096,4096] bf16
//  E : ein [4096,160] bf16 = concat(edges, nodes[s], nodes[r], g, 0pad)
//  G1: h = relu(ein @ eW1 + eb1)        [4096,4096] bf16   (128^2, swizzled)
//  G2: new_edges = relu(h @ eW2 + eb2)  -> d_out f32       (256^2 pipelined,
//       counted vmcnt(8), 1 barrier/K-tile, FIXED swizzle granule^=(row>>1)&3)
//  T3: nW1[64:8256] -> nWmT [128][4096] bf16 (after G1, over dead ein)
//  S : accb += scatter_{s|r}(new_edges @ nWmT^T)  (MFMA, A=f32->bf16 reg-staged)
//  N : new_nodes = relu(relu(nodes@nW1[0:64] + g@nW1[8256:] + nb1 + accb) @ nW2 + nb2)
// Swizzle math: LDS rows are 64B (BK=32 bf16) = 16 dword-banks; bank(row,g) =
// (16*row + 4*g) mod 32. granule g ^= (row>>1)&3 makes each 8-lane issue group
// hit 8 distinct bank-quads (enumerated for all lk groups, A and B patterns).
// Stage side (global_load_lds dest is linear): source granule = (lane&3) ^
// ((lane>>3)&3) — same involution since all row bases are multiples of 16.
// ws (70.5MB validated): accb@0 2MB (after G1; eW1T@0 dies) | nWmT@2MB 1.05MB
// (after G1; ein@2MB dies) | eW2T@3.4MB 33.5MB | h@37MB 33.5MB.
typedef unsigned short u16;
typedef unsigned int u32;
typedef unsigned long long u64;
typedef __bf16 bf16x8 __attribute__((ext_vector_type(8)));
typedef float f32x4 __attribute__((ext_vector_type(4)));

static __device__ __forceinline__ float bf2f(u16 u) {
  return __uint_as_float(((u32)u) << 16);
}
static __device__ __forceinline__ u16 f2bf(float f) {
  u32 x = __float_as_uint(f);
  return (u16)((x + 0x7fffu + ((x >> 16) & 1u)) >> 16);  // RNE
}
static __device__ __forceinline__ void gl_lds16(const u16* g, u16* l) {
  __builtin_amdgcn_global_load_lds(
      (const __attribute__((address_space(1))) void*)g,
      (__attribute__((address_space(3))) void*)l, 16, 0, 0);
}
static __device__ __forceinline__ u64 pack4bf(f32x4 v) {
  u64 r = (u64)f2bf(v[0]);
  r |= (u64)f2bf(v[1]) << 16;
  r |= (u64)f2bf(v[2]) << 32;
  r |= (u64)f2bf(v[3]) << 48;
  return r;
}

// ---------- transpose f32[K][N] -> bf16[N][Kpad], zero-pad K..Kpad ----------
__global__ __launch_bounds__(256) void k_transpose(const float* __restrict__ in,
                                                   u16* __restrict__ out,
                                                   int K, int N, int Kpad) {
  __shared__ u16 t[64 * 65];
  const int k0 = blockIdx.x * 64;
  const int n0 = blockIdx.y * 64;
  const int tid = threadIdx.x;
#pragma unroll
  for (int rep = 0; rep < 16; rep++) {
    int idx = rep * 256 + tid;
    int ki = idx >> 6, nj = idx & 63;
    float v = (k0 + ki < K) ? in[(long)(k0 + ki) * N + n0 + nj] : 0.f;
    t[ki * 65 + nj] = f2bf(v);
  }
  __syncthreads();
#pragma unroll
  for (int rep = 0; rep < 16; rep++) {
    int idx = rep * 256 + tid;
    int ni = idx >> 6, kj = idx & 63;
    if (k0 + kj < Kpad) out[(long)(n0 + ni) * Kpad + (k0 + kj)] = t[kj * 65 + ni];
  }
}

// ---------- e_in builder: [4096][160] bf16 ----------
__global__ __launch_bounds__(192) void k_build_ein(const float* __restrict__ edges,
                                                   const float* __restrict__ nodes,
                                                   const float* __restrict__ g,
                                                   const int* __restrict__ senders,
                                                   const int* __restrict__ receivers,
                                                   u16* __restrict__ ein) {
  const int e = blockIdx.x;
  const int x = threadIdx.x;
  if (x >= 160) return;
  const int s = senders[e], r = receivers[e];
  float v;
  if (x < 16) v = edges[(long)e * 16 + x];
  else if (x < 80) v = nodes[(long)s * 64 + (x - 16)];
  else if (x < 144) v = nodes[(long)r * 64 + (x - 80)];
  else if (x < 152) v = g[x - 144];
  else v = 0.f;
  ein[(long)e * 160 + x] = f2bf(v);
}

// ---------- 128^2 MFMA GEMM (G1), now with corrected swizzle ----------
template <int MODE>
__global__ __launch_bounds__(256) void k_mgemm(const u16* __restrict__ A,
                                               const u16* __restrict__ BT,
                                               const float* __restrict__ bias,
                                               void* __restrict__ C, int M, int N, int K) {
  __shared__ alignas(16) u16 As[128 * 32];
  __shared__ alignas(16) u16 Bs[128 * 32];
  const int tid = threadIdx.x;
  const int lane = tid & 63, wid = tid >> 6;
  const int wr = wid >> 1, wc = wid & 1;
  const int m0 = blockIdx.x * 128, n0 = blockIdx.y * 128;
  const int lr = lane & 15, lk = lane >> 4;
  const int swz = (lk ^ ((lr >> 1) & 3)) << 3;
  const int srow = tid >> 2;                                 // + rep*64
  const int skk = ((tid & 3) ^ ((tid >> 3) & 3)) << 3;       // swizzled source granule

  f32x4 acc[4][4];
#pragma unroll
  for (int i = 0; i < 4; i++)
#pragma unroll
    for (int j = 0; j < 4; j++) acc[i][j] = {0.f, 0.f, 0.f, 0.f};

  for (int kt = 0; kt < K; kt += 32) {
#pragma unroll
    for (int rep = 0; rep < 2; rep++) {
      int row = rep * 64 + srow;
      int o = rep * 2048 + tid * 8;
      gl_lds16(&A[(long)(m0 + row) * K + kt + skk], &As[o]);
      gl_lds16(&BT[(long)(n0 + row) * K + kt + skk], &Bs[o]);
    }
    __syncthreads();
    bf16x8 af[4], bfr[4];
#pragma unroll
    for (int mi = 0; mi < 4; mi++)
      af[mi] = *(const bf16x8*)&As[(wr * 64 + mi * 16 + lr) * 32 + swz];
#pragma unroll
    for (int ni = 0; ni < 4; ni++)
      bfr[ni] = *(const bf16x8*)&Bs[(wc * 64 + ni * 16 + lr) * 32 + swz];
#pragma unroll
    for (int mi = 0; mi < 4; mi++)
#pragma unroll
      for (int ni = 0; ni < 4; ni++)
        acc[mi][ni] =
            __builtin_amdgcn_mfma_f32_16x16x32_bf16(af[mi], bfr[ni], acc[mi][ni], 0, 0, 0);
    __syncthreads();
  }
#pragma unroll
  for (int ni = 0; ni < 4; ni++) {
    int col = n0 + wc * 64 + ni * 16 + lr;
    float bb = bias[col];
#pragma unroll
    for (int mi = 0; mi < 4; mi++) {
      int row = m0 + wr * 64 + mi * 16 + lk * 4;
#pragma unroll
      for (int r = 0; r < 4; r++) {
        float v = fmaxf(acc[mi][ni][r] + bb, 0.f);
        if (MODE == 0) ((u16*)C)[(long)(row + r) * N + col] = f2bf(v);
        else ((float*)C)[(long)(row + r) * N + col] = v;
      }
    }
  }
}

// ---------- 256^2 deep-pipelined MFMA GEMM (G2), corrected swizzle ----------
__global__ __launch_bounds__(512, 1) void k_gemm256(const u16* __restrict__ A,
                                                    const u16* __restrict__ BT,
                                                    const float* __restrict__ bias,
                                                    float* __restrict__ C, int N, int K) {
  __shared__ alignas(16) u16 lds[65536];  // 128 KB
  const int tid = threadIdx.x;
  const int lane = tid & 63, wid = tid >> 6;
  const int wr = wid >> 2, wc = wid & 3;
  const int m0 = blockIdx.x * 256, n0 = blockIdx.y * 256;
  const int lr = lane & 15, lk = lane >> 4;
  const int swz = (lk ^ ((lr >> 1) & 3)) << 3;
  const int NT = K >> 5;

  const int srow = wid * 16 + (lane >> 2);
  const int sq = ((lane & 3) ^ ((lane >> 3) & 3)) << 3;
  const int sdst = wid * 512 + lane * 8;

  f32x4 acc[8][4];
#pragma unroll
  for (int i = 0; i < 8; i++)
#pragma unroll
    for (int j = 0; j < 4; j++) acc[i][j] = {0.f, 0.f, 0.f, 0.f};

#define STAGE_TILE(T)                                                              \
  {                                                                                \
    const int kt_ = (T) * 32;                                                      \
    u16* Ab_ = &lds[((T) & 3) * 16384];                                            \
    u16* Bb_ = Ab_ + 8192;                                                         \
    gl_lds16(&A[(long)(m0 + srow) * K + kt_ + sq], Ab_ + sdst);                    \
    gl_lds16(&A[(long)(m0 + 128 + srow) * K + kt_ + sq], Ab_ + 4096 + sdst);       \
    gl_lds16(&BT[(long)(n0 + srow) * K + kt_ + sq], Bb_ + sdst);                   \
    gl_lds16(&BT[(long)(n0 + 128 + srow) * K + kt_ + sq], Bb_ + 4096 + sdst);      \
  }

  STAGE_TILE(0)
  STAGE_TILE(1)
  STAGE_TILE(2)

  for (int t = 0; t < NT; t++) {
    if (t < NT - 2) {
      asm volatile("s_waitcnt vmcnt(8)" ::: "memory");
    } else if (t == NT - 2) {
      asm volatile("s_waitcnt vmcnt(4)" ::: "memory");
    } else {
      asm volatile("s_waitcnt vmcnt(0)" ::: "memory");
    }
    __builtin_amdgcn_s_barrier();
    if (t + 3 < NT) STAGE_TILE(t + 3)

    const u16* Ab = &lds[(t & 3) * 16384];
    const u16* Bb = Ab + 8192;
    bf16x8 af[8], bfr[4];
#pragma unroll
    for (int mi = 0; mi < 8; mi++)
      af[mi] = *(const bf16x8*)&Ab[(wr * 128 + mi * 16 + lr) * 32 + swz];
#pragma unroll
    for (int ni = 0; ni < 4; ni++)
      bfr[ni] = *(const bf16x8*)&Bb[(wc * 64 + ni * 16 + lr) * 32 + swz];
#pragma unroll
    for (int mi = 0; mi < 8; mi++)
#pragma unroll
      for (int ni = 0; ni < 4; ni++)
        acc[mi][ni] =
            __builtin_amdgcn_mfma_f32_16x16x32_bf16(af[mi], bfr[ni], acc[mi][ni], 0, 0, 0);
  }
#undef STAGE_TILE

#pragma unroll
  for (int ni = 0; ni < 4; ni++) {
    int col = n0 + wc * 64 + ni * 16 + lr;
    float bb = bias[col];
#pragma unroll
    for (int mi = 0; mi < 8; mi++) {
      int row = m0 + wr * 128 + mi * 16 + lk * 4;
#pragma unroll
      for (int r = 0; r < 4; r++)
        C[(long)(row + r) * N + col] = fmaxf(acc[mi][ni][r] + bb, 0.f);
    }
  }
}

// ---------- MFMA scatter-GEMM: accb += scatter(new_edges @ [Ws|Wr]) ----------
// E f32 [4096][4096] (d_out); BT = nWmT bf16 [128][4096]. Per block: 128 edge
// rows x all 128 cols, K chunk 512. A staged reg->cvt->ds_write (swizzled);
// B via gl_lds16 (swizzled source). Epilogue: cols 0-63 -> senders target,
// 64-127 -> receivers. grid (32, 8).
__global__ __launch_bounds__(256) void k_scatter_m(const float* __restrict__ E,
                                                   const u16* __restrict__ BT,
                                                   const int* __restrict__ senders,
                                                   const int* __restrict__ receivers,
                                                   float* __restrict__ accb) {
  const int K = 4096;
  __shared__ alignas(16) u16 As[128 * 32];
  __shared__ alignas(16) u16 Bs[128 * 32];
  const int tid = threadIdx.x;
  const int lane = tid & 63, wid = tid >> 6;
  const int wr = wid >> 1, wc = wid & 1;
  const int m0 = blockIdx.x * 128;
  const int kbase = blockIdx.y * 512;
  const int lr = lane & 15, lk = lane >> 4;
  const int swz = (lk ^ ((lr >> 1) & 3)) << 3;
  const int srow = tid >> 2;
  const int skk = ((tid & 3) ^ ((tid >> 3) & 3)) << 3;

  f32x4 acc[4][4];
#pragma unroll
  for (int i = 0; i < 4; i++)
#pragma unroll
    for (int j = 0; j < 4; j++) acc[i][j] = {0.f, 0.f, 0.f, 0.f};

  for (int kt = kbase; kt < kbase + 512; kt += 32) {
    // A: f32 -> bf16, swizzled LDS write (8B per thread per pass)
#pragma unroll
    for (int p = 0; p < 4; p++) {
      int idx = p * 256 + tid;  // 0..1023
      int r = idx >> 3;         // 0..127
      int kq = idx & 7;         // 8B quad within 64B row
      f32x4 v = *(const f32x4*)&E[(long)(m0 + r) * 4096 + kt + kq * 4];
      int gq = (kq >> 1) ^ ((r >> 1) & 3);
      *(u64*)&As[r * 32 + gq * 8 + (kq & 1) * 4] = pack4bf(v);
    }
    // B: swizzled-source DMA
#pragma unroll
    for (int rep = 0; rep < 2; rep++) {
      int row = rep * 64 + srow;
      gl_lds16(&BT[(long)row * K + kt + skk], &Bs[rep * 2048 + tid * 8]);
    }
    __syncthreads();
    bf16x8 af[4], bfr[4];
#pragma unroll
    for (int mi = 0; mi < 4; mi++)
      af[mi] = *(const bf16x8*)&As[(wr * 64 + mi * 16 + lr) * 32 + swz];
#pragma unroll
    for (int ni = 0; ni < 4; ni++)
      bfr[ni] = *(const bf16x8*)&Bs[(wc * 64 + ni * 16 + lr) * 32 + swz];
#pragma unroll
    for (int mi = 0; mi < 4; mi++)
#pragma unroll
      for (int ni = 0; ni < 4; ni++)
        acc[mi][ni] =
            __builtin_amdgcn_mfma_f32_16x16x32_bf16(af[mi], bfr[ni], acc[mi][ni], 0, 0, 0);
    __syncthreads();
  }
  // scatter epilogue: col<64 -> senders (W_s), col>=64 -> receivers (W_r)
#pragma unroll
  for (int mi = 0; mi < 4; mi++) {
#pragma unroll
    for (int r = 0; r < 4; r++) {
      int e = m0 + wr * 64 + mi * 16 + lk * 4 + r;
#pragma unroll
      for (int ni = 0; ni < 4; ni++) {
        int col = wc * 64 + ni * 16 + lr;
        int tgt = (col < 64) ? senders[e] : receivers[e];
        atomicAdd(&accb[(long)tgt * 64 + (col & 63)], acc[mi][ni][r]);
      }
    }
  }
}

// ---------- final node MLP, pure f32 (round-6 validated) ----------
__global__ __launch_bounds__(256) void k_final(const float* __restrict__ nodes,
                                               const float* __restrict__ g,
                                               const float* __restrict__ nW1,
                                               const float* __restrict__ nb1,
                                               const float* __restrict__ nW2,
                                               const float* __restrict__ nb2,
                                               const float* __restrict__ zpre,
                                               float* __restrict__ out0) {
  __shared__ float h2[64 * 64];
  __shared__ float gb[64];
  const int tid = threadIdx.x;
  const long n0 = (long)blockIdx.x * 64;
  if (tid < 64) {
    float s = nb1[tid];
#pragma unroll
    for (int j = 0; j < 8; j++) s += g[j] * nW1[(long)(8256 + j) * 64 + tid];
    gb[tid] = s;
  }
  __syncthreads();
#pragma unroll 2
  for (int rep = 0; rep < 16; rep++) {
    int idx = rep * 256 + tid;
    int i = idx >> 6, c = idx & 63;
    float z = gb[c] + zpre[(n0 + i) * 64 + c];
    const float* nr = nodes + (n0 + i) * 64;
#pragma unroll 8
    for (int k = 0; k < 64; k++) z += nr[k] * nW1[(long)k * 64 + c];
    h2[idx] = fmaxf(z, 0.f);
  }
  __syncthreads();
#pragma unroll 2
  for (int rep = 0; rep < 16; rep++) {
    int idx = rep * 256 + tid;
    int i = idx >> 6, c = idx & 63;
    float z = nb2[c];
#pragma unroll 8
    for (int k = 0; k < 64; k++) z += h2[i * 64 + k] * nW2[(long)k * 64 + c];
    out0[(n0 + i) * 64 + c] = fmaxf(z, 0.f);
  }
}

extern "C" void kernel_launch(void* const* d_in, const int* in_sizes, int n_in,
                              void* d_out, int out_size, void* d_ws, size_t ws_size,
                              hipStream_t stream) {
  const float* nodes = (const float*)d_in[0];
  const float* edges = (const float*)d_in[1];
  const float* g = (const float*)d_in[2];
  const int* senders = (const int*)d_in[3];
  const int* receivers = (const int*)d_in[4];
  const float* eW1 = (const float*)d_in[5];
  const float* eb1 = (const float*)d_in[6];
  const float* eW2 = (const float*)d_in[7];
  const float* eb2 = (const float*)d_in[8];
  const float* nW1 = (const float*)d_in[9];
  const float* nb1 = (const float*)d_in[10];
  const float* nW2 = (const float*)d_in[11];
  const float* nb2 = (const float*)d_in[12];

  char* ws = (char*)d_ws;
  u16* eW1T = (u16*)(ws + 0);        // [4096][160] bf16, dies after G1
  float* accb = (float*)(ws + 0);    // [8192][64] f32, live after memset (post-G1)
  u16* ein = (u16*)(ws + 2097152);   // [4096][160] bf16, dies after G1
  u16* nWmT = (u16*)(ws + 2097152);  // [128][4096] bf16, written after G1
  u16* eW2T = (u16*)(ws + 3407872);  // [4096][4096] bf16
  u16* h = (u16*)(ws + 36962304);    // [4096][4096] bf16  (ends 70.5MB)

  float* out_nodes = (float*)d_out;
  float* out_edges = (float*)d_out + 524288;

  dim3 b256(256);
  k_transpose<<<dim3(3, 64), b256, 0, stream>>>(eW1, eW1T, 152, 4096, 160);
  k_transpose<<<dim3(64, 64), b256, 0, stream>>>(eW2, eW2T, 4096, 4096, 4096);
  k_build_ein<<<4096, 192, 0, stream>>>(edges, nodes, g, senders, receivers, ein);

  k_mgemm<0><<<dim3(32, 32), b256, 0, stream>>>(ein, eW1T, eb1, h, 4096, 4096, 160);

  // ein/eW1T dead: build nWmT + clear accb while G2's inputs are untouched.
  k_transpose<<<dim3(64, 1), b256, 0, stream>>>(nW1 + 64 * 64, nWmT, 4096, 64, 4096);
  k_transpose<<<dim3(64, 1), b256, 0, stream>>>(nW1 + 4160 * 64, nWmT + (long)64 * 4096,
                                                4096, 64, 4096);
  hipMemsetAsync(accb, 0, 8192 * 64 * 4, stream);

  k_gemm256<<<dim3(16, 16), dim3(512), 0, stream>>>(h, eW2T, eb2, out_edges, 4096, 4096);

  k_scatter_m<<<dim3(32, 8), b256, 0, stream>>>(out_edges, nWmT, senders, receivers, accb);
  k_final<<<128, b256, 0, stream>>>(nodes, g, nW1, nb1, nW2, nb2, accb, out_nodes);
}